// Round 1
// baseline (5475.809 us; speedup 1.0000x reference)
//
#include <hip/hip_runtime.h>

#define H 128
#define H2 256
#define NODE_IN 32
#define BN_EPS 1e-5f

// ---------------------------------------------------------------------------
// h = x @ emb_W + emb_b ; writes h to both out (h) and z (next z-init)
// block: 256 threads, 16 rows per block
__global__ __launch_bounds__(256) void embed_kernel(
    const float* __restrict__ x, const float* __restrict__ W,
    const float* __restrict__ bias, float* __restrict__ h,
    float* __restrict__ z, int N)
{
    __shared__ float xs[16][NODE_IN + 4];
    int row0 = blockIdx.x * 16;
    int t = threadIdx.x;
    if (t < 128) {
        int r = t >> 3, c4 = t & 7;
        int gr = row0 + r;
        float4 v = make_float4(0.f, 0.f, 0.f, 0.f);
        if (gr < N) v = *(const float4*)&x[(size_t)gr * NODE_IN + c4 * 4];
        *(float4*)&xs[r][c4 * 4] = v;
    }
    __syncthreads();
    int c = t & (H - 1);
    int rg = t >> 7;          // 0..1
    int r0 = rg * 8;
    float acc[8] = {0, 0, 0, 0, 0, 0, 0, 0};
    for (int k = 0; k < NODE_IN; ++k) {
        float w = W[k * H + c];
#pragma unroll
        for (int r = 0; r < 8; ++r) acc[r] += xs[r0 + r][k] * w;
    }
    float bb = bias[c];
#pragma unroll
    for (int r = 0; r < 8; ++r) {
        int gr = row0 + r0 + r;
        if (gr < N) {
            float v = acc[r] + bb;
            h[(size_t)gr * H + c] = v;
            z[(size_t)gr * H + c] = v;
        }
    }
}

// ---------------------------------------------------------------------------
// z[dst] += h[src] over all edges. 32 threads per edge (4 floats each).
__global__ __launch_bounds__(256) void scatter_kernel(
    const float* __restrict__ h, const int* __restrict__ src,
    const int* __restrict__ dst, float* __restrict__ z, int E)
{
    int gid = blockIdx.x * 256 + threadIdx.x;
    int e = gid >> 5;
    if (e >= E) return;
    int f4 = gid & 31;
    int s = src[e], d = dst[e];
    float4 v = *(const float4*)&h[(size_t)s * H + f4 * 4];
    float* zp = &z[(size_t)d * H + f4 * 4];
    atomicAdd(zp + 0, v.x);
    atomicAdd(zp + 1, v.y);
    atomicAdd(zp + 2, v.z);
    atomicAdd(zp + 3, v.w);
}

// ---------------------------------------------------------------------------
// In-place fused MLP: z <- relu(z@W1+b1)@W2+b2 (pre-BN), BN partial stats
// block: 256 threads = 64 colgroups x 4 rowgroups; 32 rows per block
#define TM 32
__global__ __launch_bounds__(256) void mlp_kernel(
    float* __restrict__ z, const float* __restrict__ W1l,
    const float* __restrict__ b1l, const float* __restrict__ W2l,
    const float* __restrict__ b2l, float* __restrict__ stats, int N)
{
    __shared__ float zt[TM][H + 4];    // stride 132 floats (16B aligned)
    __shared__ float hid[TM][H2 + 4];  // stride 260 floats (16B aligned)

    int row0 = blockIdx.x * TM;
    int t = threadIdx.x;

    // ---- phase 1: stage z tile ----
    for (int i = t; i < TM * (H / 4); i += 256) {
        int r = i >> 5, c4 = i & 31;
        int gr = row0 + r;
        float4 v = make_float4(0.f, 0.f, 0.f, 0.f);
        if (gr < N) v = *(const float4*)&z[(size_t)gr * H + c4 * 4];
        *(float4*)&zt[r][c4 * 4] = v;
    }
    __syncthreads();

    int cg = t & 63;   // colgroup
    int rg = t >> 6;   // rowgroup (wave-uniform)
    int r0 = rg * 8;

    // ---- phase 2: hid = relu(zt @ W1 + b1), cols j0..j0+3 ----
    int j0 = cg * 4;
    float acc[8][4];
#pragma unroll
    for (int r = 0; r < 8; ++r)
#pragma unroll
        for (int c = 0; c < 4; ++c) acc[r][c] = 0.f;

    for (int k = 0; k < H; k += 4) {
        float4 wa = *(const float4*)&W1l[(size_t)(k + 0) * H2 + j0];
        float4 wb = *(const float4*)&W1l[(size_t)(k + 1) * H2 + j0];
        float4 wc = *(const float4*)&W1l[(size_t)(k + 2) * H2 + j0];
        float4 wd = *(const float4*)&W1l[(size_t)(k + 3) * H2 + j0];
#pragma unroll
        for (int r = 0; r < 8; ++r) {
            float4 zv = *(const float4*)&zt[r0 + r][k];
            acc[r][0] += zv.x * wa.x + zv.y * wb.x + zv.z * wc.x + zv.w * wd.x;
            acc[r][1] += zv.x * wa.y + zv.y * wb.y + zv.z * wc.y + zv.w * wd.y;
            acc[r][2] += zv.x * wa.z + zv.y * wb.z + zv.z * wc.z + zv.w * wd.z;
            acc[r][3] += zv.x * wa.w + zv.y * wb.w + zv.z * wc.w + zv.w * wd.w;
        }
    }
    {
        float4 b1v = *(const float4*)&b1l[j0];
#pragma unroll
        for (int r = 0; r < 8; ++r) {
            float4 v;
            v.x = fmaxf(acc[r][0] + b1v.x, 0.f);
            v.y = fmaxf(acc[r][1] + b1v.y, 0.f);
            v.z = fmaxf(acc[r][2] + b1v.z, 0.f);
            v.w = fmaxf(acc[r][3] + b1v.w, 0.f);
            *(float4*)&hid[r0 + r][j0] = v;
        }
    }
    __syncthreads();

    // ---- phase 3: out = hid @ W2 + b2, cols j1..j1+1 ----
    int j1 = cg * 2;
    float acc2[8][2];
#pragma unroll
    for (int r = 0; r < 8; ++r) { acc2[r][0] = 0.f; acc2[r][1] = 0.f; }

    for (int k = 0; k < H2; k += 4) {
        float2 wa = *(const float2*)&W2l[(size_t)(k + 0) * H + j1];
        float2 wb = *(const float2*)&W2l[(size_t)(k + 1) * H + j1];
        float2 wc = *(const float2*)&W2l[(size_t)(k + 2) * H + j1];
        float2 wd = *(const float2*)&W2l[(size_t)(k + 3) * H + j1];
#pragma unroll
        for (int r = 0; r < 8; ++r) {
            float4 hv = *(const float4*)&hid[r0 + r][k];
            acc2[r][0] += hv.x * wa.x + hv.y * wb.x + hv.z * wc.x + hv.w * wd.x;
            acc2[r][1] += hv.x * wa.y + hv.y * wb.y + hv.z * wc.y + hv.w * wd.y;
        }
    }

    float2 b2v = *(const float2*)&b2l[j1];
    float ps0 = 0.f, ps1 = 0.f, pq0 = 0.f, pq1 = 0.f;
#pragma unroll
    for (int r = 0; r < 8; ++r) {
        int gr = row0 + r0 + r;
        if (gr < N) {
            float v0 = acc2[r][0] + b2v.x;
            float v1 = acc2[r][1] + b2v.y;
            *(float2*)&z[(size_t)gr * H + j1] = make_float2(v0, v1);
            ps0 += v0; pq0 += v0 * v0;
            ps1 += v1; pq1 += v1 * v1;
        }
    }
    atomicAdd(&stats[j1 + 0], ps0);
    atomicAdd(&stats[j1 + 1], ps1);
    atomicAdd(&stats[H + j1 + 0], pq0);
    atomicAdd(&stats[H + j1 + 1], pq1);
}

// ---------------------------------------------------------------------------
__global__ void bn_finalize_kernel(const float* __restrict__ stats,
                                   const float* __restrict__ gamma,
                                   const float* __restrict__ beta,
                                   float* __restrict__ ss, int N)
{
    int j = threadIdx.x;
    float invN = 1.0f / (float)N;
    float mean = stats[j] * invN;
    float var = stats[H + j] * invN - mean * mean;
    float sc = gamma[j] * rsqrtf(var + BN_EPS);
    ss[j] = sc;
    ss[H + j] = beta[j] - mean * sc;
}

// ---------------------------------------------------------------------------
// h = relu(z*scale + shift); optionally also re-init z = h for next layer
__global__ __launch_bounds__(256) void bn_apply_kernel(
    float* __restrict__ z, const float* __restrict__ ss,
    float* __restrict__ h, int N, int writeZ)
{
    size_t i = (size_t)blockIdx.x * 256 + threadIdx.x;  // float4 index
    size_t total = (size_t)N * (H / 4);
    if (i >= total) return;
    int c4 = (int)(i & (H / 4 - 1));
    float4 v = ((const float4*)z)[i];
    float4 sc = *(const float4*)&ss[c4 * 4];
    float4 sh = *(const float4*)&ss[H + c4 * 4];
    float4 r;
    r.x = fmaxf(v.x * sc.x + sh.x, 0.f);
    r.y = fmaxf(v.y * sc.y + sh.y, 0.f);
    r.z = fmaxf(v.z * sc.z + sh.z, 0.f);
    r.w = fmaxf(v.w * sc.w + sh.w, 0.f);
    ((float4*)h)[i] = r;
    if (writeZ) ((float4*)z)[i] = r;
}

// ---------------------------------------------------------------------------
extern "C" void kernel_launch(void* const* d_in, const int* in_sizes, int n_in,
                              void* d_out, int out_size, void* d_ws, size_t ws_size,
                              hipStream_t stream)
{
    const float* x    = (const float*)d_in[0];
    const int*   ei   = (const int*)d_in[1];
    const float* embW = (const float*)d_in[2];
    const float* embb = (const float*)d_in[3];
    const float* W1   = (const float*)d_in[4];
    const float* b1   = (const float*)d_in[5];
    const float* W2   = (const float*)d_in[6];
    const float* b2   = (const float*)d_in[7];
    const float* gamma= (const float*)d_in[8];
    const float* beta = (const float*)d_in[9];

    int N = in_sizes[0] / NODE_IN;
    int E = in_sizes[1] / 2;
    int L = in_sizes[4] / (H * H2);
    const int* src = ei;
    const int* dst = ei + E;

    float* h = (float*)d_out;
    float* z = (float*)d_ws;
    float* stats = z + (size_t)N * H;
    float* ss = stats + 2 * H;

    embed_kernel<<<(N + 15) / 16, 256, 0, stream>>>(x, embW, embb, h, z, N);

    for (int l = 0; l < L; ++l) {
        hipMemsetAsync(stats, 0, 2 * H * sizeof(float), stream);
        int sgrid = (E * 32 + 255) / 256;
        scatter_kernel<<<sgrid, 256, 0, stream>>>(h, src, dst, z, E);
        mlp_kernel<<<(N + TM - 1) / TM, 256, 0, stream>>>(
            z, W1 + (size_t)l * H * H2, b1 + (size_t)l * H2,
            W2 + (size_t)l * H2 * H, b2 + (size_t)l * H, stats, N);
        bn_finalize_kernel<<<1, H, 0, stream>>>(
            stats, gamma + (size_t)l * H, beta + (size_t)l * H, ss, N);
        int agrid = (int)(((size_t)N * (H / 4) + 255) / 256);
        bn_apply_kernel<<<agrid, 256, 0, stream>>>(z, ss, h, N, (l < L - 1) ? 1 : 0);
    }
}

// Round 2
// 1012.422 us; speedup vs baseline: 5.4086x; 5.4086x over previous
//
#include <hip/hip_runtime.h>

#define H 128
#define H2 256
#define NODE_IN 32
#define BN_EPS 1e-5f

typedef __bf16 bf16x8 __attribute__((ext_vector_type(8)));
typedef float f32x4 __attribute__((ext_vector_type(4)));

#define HS 264  // hid LDS row stride in bf16 elements (528 B, 16B-aligned, conflict-free b128 reads)

// ---------------------------------------------------------------------------
// Convert W1 [L][128][256] -> W1t [L][256][128] bf16 ; W2 [L][256][128] -> W2t [L][128][256] bf16
__global__ __launch_bounds__(256) void convert_weights_kernel(
    const float* __restrict__ W1, const float* __restrict__ W2,
    __bf16* __restrict__ W1t, __bf16* __restrict__ W2t, int L)
{
    int idx = blockIdx.x * 256 + threadIdx.x;
    int per = H * H2;
    int total = L * per;
    if (idx < total) {
        int l = idx / per, r = idx % per;
        int k = r / H2, n = r % H2;                     // W1[l][k][n]
        W1t[(size_t)l * per + (size_t)n * H + k] = (__bf16)W1[idx];
    } else if (idx < 2 * total) {
        int j = idx - total;
        int l = j / per, r = j % per;
        int k = r / H, n = r % H;                       // W2[l][k][n]
        W2t[(size_t)l * per + (size_t)n * H2 + k] = (__bf16)W2[j];
    }
}

// ---------------------------------------------------------------------------
// h = x @ emb_W + emb_b
__global__ __launch_bounds__(256) void embed_kernel(
    const float* __restrict__ x, const float* __restrict__ W,
    const float* __restrict__ bias, float* __restrict__ h, int N)
{
    __shared__ float xs[16][NODE_IN + 4];
    int row0 = blockIdx.x * 16;
    int t = threadIdx.x;
    if (t < 128) {
        int r = t >> 3, c4 = t & 7;
        int gr = row0 + r;
        float4 v = make_float4(0.f, 0.f, 0.f, 0.f);
        if (gr < N) v = *(const float4*)&x[(size_t)gr * NODE_IN + c4 * 4];
        *(float4*)&xs[r][c4 * 4] = v;
    }
    __syncthreads();
    int c = t & (H - 1);
    int rg = t >> 7;
    int r0 = rg * 8;
    float acc[8] = {0, 0, 0, 0, 0, 0, 0, 0};
    for (int k = 0; k < NODE_IN; ++k) {
        float w = W[k * H + c];
#pragma unroll
        for (int r = 0; r < 8; ++r) acc[r] += xs[r0 + r][k] * w;
    }
    float bb = bias[c];
#pragma unroll
    for (int r = 0; r < 8; ++r) {
        int gr = row0 + r0 + r;
        if (gr < N) h[(size_t)gr * H + c] = acc[r] + bb;
    }
}

// ---------------------------------------------------------------------------
// CSR build: histogram, single-block scan, fill
__global__ __launch_bounds__(256) void hist_kernel(
    const int* __restrict__ dst, int* __restrict__ deg, int E)
{
    int e = blockIdx.x * 256 + threadIdx.x;
    if (e < E) atomicAdd(&deg[dst[e]], 1);
}

__global__ __launch_bounds__(1024) void scan_kernel(
    const int* __restrict__ deg, int* __restrict__ offp, int N)
{
    __shared__ int ts[1024];
    int t = threadIdx.x;
    int chunk = (N + 1023) >> 10;
    int s0 = t * chunk;
    int s1 = s0 + chunk; if (s1 > N) s1 = N;
    int sum = 0;
    for (int i = s0; i < s1; ++i) sum += deg[i];
    ts[t] = sum;
    __syncthreads();
    for (int d = 1; d < 1024; d <<= 1) {
        int v = (t >= d) ? ts[t - d] : 0;
        __syncthreads();
        ts[t] += v;
        __syncthreads();
    }
    int run = (t == 0) ? 0 : ts[t - 1];
    for (int i = s0; i < s1; ++i) { offp[i] = run; run += deg[i]; }
    if (t == 1023) offp[N] = run;
}

__global__ __launch_bounds__(256) void fill_kernel(
    const int* __restrict__ src, const int* __restrict__ dst,
    int* __restrict__ cursor, int* __restrict__ srclist, int E)
{
    int e = blockIdx.x * 256 + threadIdx.x;
    if (e < E) {
        int pos = atomicAdd(&cursor[dst[e]], 1);
        srclist[pos] = src[e];
    }
}

// ---------------------------------------------------------------------------
// z[v] = h[v] + sum_{neighbors} h[src]; 32 lanes per node, float4/lane
__global__ __launch_bounds__(256) void gather_kernel(
    const float* __restrict__ h, const int* __restrict__ offp,
    const int* __restrict__ srclist, float* __restrict__ z, int N)
{
    int gid = blockIdx.x * 256 + threadIdx.x;
    int v = gid >> 5;
    if (v >= N) return;
    int c4 = (gid & 31) * 4;
    float4 acc = *(const float4*)&h[(size_t)v * H + c4];
    int i0 = offp[v], i1 = offp[v + 1];
    for (int i = i0; i < i1; ++i) {
        int s = srclist[i];
        float4 u = *(const float4*)&h[(size_t)s * H + c4];
        acc.x += u.x; acc.y += u.y; acc.z += u.z; acc.w += u.w;
    }
    *(float4*)&z[(size_t)v * H + c4] = acc;
}

// ---------------------------------------------------------------------------
// MFMA MLP: z <- relu(z@W1+b1)@W2+b2 (pre-BN, in-place), BN partial stats.
// 256 threads = 4 waves; 16 rows/wave, 64 rows/block.
__global__ __launch_bounds__(256) void mlp_mfma_kernel(
    float* __restrict__ z, const __bf16* __restrict__ W1t,
    const float* __restrict__ b1l, const __bf16* __restrict__ W2t,
    const float* __restrict__ b2l, float* __restrict__ stats, int N)
{
    __shared__ __bf16 hid[4][16 * HS];
    __shared__ float sstat[2 * H];

    int t = threadIdx.x;
    int w = t >> 6, lane = t & 63;
    int l15 = lane & 15, kg = lane >> 4;
    int rbase = blockIdx.x * 64 + w * 16;
    int r = rbase + l15;

    sstat[t] = 0.f;   // 2*H == 256 == blockDim

    // ---- A fragments from z (fp32 -> bf16) ----
    bf16x8 a[4];
    const float* zrow = z + (size_t)r * H;
    bool rok = (r < N);
#pragma unroll
    for (int kk = 0; kk < 4; ++kk) {
        float4 v0 = make_float4(0.f, 0.f, 0.f, 0.f), v1 = v0;
        if (rok) {
            v0 = *(const float4*)&zrow[kk * 32 + kg * 8];
            v1 = *(const float4*)&zrow[kk * 32 + kg * 8 + 4];
        }
        a[kk][0] = (__bf16)v0.x; a[kk][1] = (__bf16)v0.y;
        a[kk][2] = (__bf16)v0.z; a[kk][3] = (__bf16)v0.w;
        a[kk][4] = (__bf16)v1.x; a[kk][5] = (__bf16)v1.y;
        a[kk][6] = (__bf16)v1.z; a[kk][7] = (__bf16)v1.w;
    }

    __bf16* hw = &hid[w][0];

    // ---- GEMM1: hid = relu(z @ W1 + b1), 16 col-tiles of 16 ----
#pragma unroll
    for (int nt = 0; nt < 16; ++nt) {
        f32x4 acc = {0.f, 0.f, 0.f, 0.f};
        int c = nt * 16 + l15;
        const __bf16* bp = W1t + (size_t)c * H + kg * 8;
#pragma unroll
        for (int kk = 0; kk < 4; ++kk) {
            bf16x8 b = *(const bf16x8*)(bp + kk * 32);
            acc = __builtin_amdgcn_mfma_f32_16x16x32_bf16(a[kk], b, acc, 0, 0, 0);
        }
        float bb = b1l[c];
#pragma unroll
        for (int q = 0; q < 4; ++q) {
            float v = fmaxf(acc[q] + bb, 0.f);
            hw[(kg * 4 + q) * HS + c] = (__bf16)v;
        }
    }
    __syncthreads();   // hid visible; sstat zeroed before epilogue atomics

    // ---- A2 fragments from LDS ----
    bf16x8 a2[8];
#pragma unroll
    for (int kk = 0; kk < 8; ++kk)
        a2[kk] = *(const bf16x8*)&hw[l15 * HS + kk * 32 + kg * 8];

    // ---- GEMM2 + epilogue: z = hid @ W2 + b2, BN partial stats ----
#pragma unroll
    for (int nt = 0; nt < 8; ++nt) {
        f32x4 acc = {0.f, 0.f, 0.f, 0.f};
        int c = nt * 16 + l15;
        const __bf16* bp = W2t + (size_t)c * H2 + kg * 8;
#pragma unroll
        for (int kk = 0; kk < 8; ++kk) {
            bf16x8 b = *(const bf16x8*)(bp + kk * 32);
            acc = __builtin_amdgcn_mfma_f32_16x16x32_bf16(a2[kk], b, acc, 0, 0, 0);
        }
        float bb = b2l[c];
        float ps = 0.f, pq = 0.f;
#pragma unroll
        for (int q = 0; q < 4; ++q) {
            int row = rbase + kg * 4 + q;
            if (row < N) {
                float v = acc[q] + bb;
                z[(size_t)row * H + c] = v;
                ps += v; pq += v * v;
            }
        }
        ps += __shfl_xor(ps, 16); ps += __shfl_xor(ps, 32);
        pq += __shfl_xor(pq, 16); pq += __shfl_xor(pq, 32);
        if (kg == 0) {
            atomicAdd(&sstat[c], ps);
            atomicAdd(&sstat[H + c], pq);
        }
    }
    __syncthreads();
    atomicAdd(&stats[t], sstat[t]);
}

// ---------------------------------------------------------------------------
__global__ void bn_finalize_kernel(const float* __restrict__ stats,
                                   const float* __restrict__ gamma,
                                   const float* __restrict__ beta,
                                   float* __restrict__ ss, int N)
{
    int j = threadIdx.x;
    float invN = 1.0f / (float)N;
    float mean = stats[j] * invN;
    float var = stats[H + j] * invN - mean * mean;
    float sc = gamma[j] * rsqrtf(var + BN_EPS);
    ss[j] = sc;
    ss[H + j] = beta[j] - mean * sc;
}

// ---------------------------------------------------------------------------
// h = relu(z*scale + shift)
__global__ __launch_bounds__(256) void bn_apply_kernel(
    const float* __restrict__ z, const float* __restrict__ ss,
    float* __restrict__ h, int N)
{
    size_t i = (size_t)blockIdx.x * 256 + threadIdx.x;
    size_t total = (size_t)N * (H / 4);
    if (i >= total) return;
    int c4 = (int)(i & (H / 4 - 1));
    float4 v = ((const float4*)z)[i];
    float4 sc = *(const float4*)&ss[c4 * 4];
    float4 sh = *(const float4*)&ss[H + c4 * 4];
    float4 r;
    r.x = fmaxf(v.x * sc.x + sh.x, 0.f);
    r.y = fmaxf(v.y * sc.y + sh.y, 0.f);
    r.z = fmaxf(v.z * sc.z + sh.z, 0.f);
    r.w = fmaxf(v.w * sc.w + sh.w, 0.f);
    ((float4*)h)[i] = r;
}

// ---------------------------------------------------------------------------
static inline char* align_up(char* p, size_t a) {
    return (char*)(((uintptr_t)p + a - 1) & ~(uintptr_t)(a - 1));
}

extern "C" void kernel_launch(void* const* d_in, const int* in_sizes, int n_in,
                              void* d_out, int out_size, void* d_ws, size_t ws_size,
                              hipStream_t stream)
{
    const float* x    = (const float*)d_in[0];
    const int*   ei   = (const int*)d_in[1];
    const float* embW = (const float*)d_in[2];
    const float* embb = (const float*)d_in[3];
    const float* W1   = (const float*)d_in[4];
    const float* b1   = (const float*)d_in[5];
    const float* W2   = (const float*)d_in[6];
    const float* b2   = (const float*)d_in[7];
    const float* gamma= (const float*)d_in[8];
    const float* beta = (const float*)d_in[9];

    int N = in_sizes[0] / NODE_IN;
    int E = in_sizes[1] / 2;
    int L = in_sizes[4] / (H * H2);
    const int* src = ei;
    const int* dst = ei + E;

    char* w = (char*)d_ws;
    float* z = (float*)w;        w += (size_t)N * H * sizeof(float);
    w = align_up(w, 256);
    float* stats = (float*)w;    w += 2 * H * sizeof(float);
    float* ss = (float*)w;       w += 2 * H * sizeof(float);
    int* deg = (int*)w;          w += (size_t)N * sizeof(int);
    int* offp = (int*)w;         w += (size_t)(N + 1) * sizeof(int);
    int* cursor = (int*)w;       w += (size_t)N * sizeof(int);
    int* srcl = (int*)w;         w += (size_t)E * sizeof(int);
    w = align_up(w, 256);
    __bf16* W1t = (__bf16*)w;    w += (size_t)L * H * H2 * sizeof(__bf16);
    w = align_up(w, 256);
    __bf16* W2t = (__bf16*)w;    w += (size_t)L * H * H2 * sizeof(__bf16);

    float* h = (float*)d_out;

    // once-per-launch prep
    int wtotal2 = 2 * L * H * H2;
    convert_weights_kernel<<<(wtotal2 + 255) / 256, 256, 0, stream>>>(W1, W2, W1t, W2t, L);
    embed_kernel<<<(N + 15) / 16, 256, 0, stream>>>(x, embW, embb, h, N);

    hipMemsetAsync(deg, 0, (size_t)N * sizeof(int), stream);
    hist_kernel<<<(E + 255) / 256, 256, 0, stream>>>(dst, deg, E);
    scan_kernel<<<1, 1024, 0, stream>>>(deg, offp, N);
    hipMemcpyAsync(cursor, offp, (size_t)N * sizeof(int), hipMemcpyDeviceToDevice, stream);
    fill_kernel<<<(E + 255) / 256, 256, 0, stream>>>(src, dst, cursor, srcl, E);

    int ggrid = (N * 32 + 255) / 256;
    int mgrid = (N + 63) / 64;
    int agrid = (int)(((size_t)N * (H / 4) + 255) / 256);

    for (int l = 0; l < L; ++l) {
        gather_kernel<<<ggrid, 256, 0, stream>>>(h, offp, srcl, z, N);
        hipMemsetAsync(stats, 0, 2 * H * sizeof(float), stream);
        mlp_mfma_kernel<<<mgrid, 256, 0, stream>>>(
            z, W1t + (size_t)l * H * H2, b1 + (size_t)l * H2,
            W2t + (size_t)l * H * H2, b2 + (size_t)l * H, stats, N);
        bn_finalize_kernel<<<1, H, 0, stream>>>(
            stats, gamma + (size_t)l * H, beta + (size_t)l * H, ss, N);
        bn_apply_kernel<<<agrid, 256, 0, stream>>>(z, ss, h, N);
    }
}

// Round 3
// 664.552 us; speedup vs baseline: 8.2398x; 1.5235x over previous
//
#include <hip/hip_runtime.h>

#define H 128
#define H2 256
#define NODE_IN 32
#define BN_EPS 1e-5f

typedef __bf16 bf16x8 __attribute__((ext_vector_type(8)));
typedef float f32x4 __attribute__((ext_vector_type(4)));

#define HS 264  // hid LDS row stride in bf16 (528 B, 16B-aligned, spreads banks)

// ---------------------------------------------------------------------------
// W1 [L][128][256] -> W1t [L][256][128] bf16 ; W2 [L][256][128] -> W2t [L][128][256] bf16
__global__ __launch_bounds__(256) void convert_weights_kernel(
    const float* __restrict__ W1, const float* __restrict__ W2,
    __bf16* __restrict__ W1t, __bf16* __restrict__ W2t, int L)
{
    int idx = blockIdx.x * 256 + threadIdx.x;
    int per = H * H2;
    int total = L * per;
    if (idx < total) {
        int l = idx / per, r = idx % per;
        int k = r / H2, n = r % H2;                     // W1[l][k][n]
        W1t[(size_t)l * per + (size_t)n * H + k] = (__bf16)W1[idx];
    } else if (idx < 2 * total) {
        int j = idx - total;
        int l = j / per, r = j % per;
        int k = r / H, n = r % H;                       // W2[l][k][n]
        W2t[(size_t)l * per + (size_t)n * H2 + k] = (__bf16)W2[j];
    }
}

// ---------------------------------------------------------------------------
__global__ __launch_bounds__(256) void embed_kernel(
    const float* __restrict__ x, const float* __restrict__ W,
    const float* __restrict__ bias, float* __restrict__ h, int N)
{
    __shared__ float xs[16][NODE_IN + 4];
    int row0 = blockIdx.x * 16;
    int t = threadIdx.x;
    if (t < 128) {
        int r = t >> 3, c4 = t & 7;
        int gr = row0 + r;
        float4 v = make_float4(0.f, 0.f, 0.f, 0.f);
        if (gr < N) v = *(const float4*)&x[(size_t)gr * NODE_IN + c4 * 4];
        *(float4*)&xs[r][c4 * 4] = v;
    }
    __syncthreads();
    int c = t & (H - 1);
    int rg = t >> 7;
    int r0 = rg * 8;
    float acc[8] = {0, 0, 0, 0, 0, 0, 0, 0};
    for (int k = 0; k < NODE_IN; ++k) {
        float w = W[k * H + c];
#pragma unroll
        for (int r = 0; r < 8; ++r) acc[r] += xs[r0 + r][k] * w;
    }
    float bb = bias[c];
#pragma unroll
    for (int r = 0; r < 8; ++r) {
        int gr = row0 + r0 + r;
        if (gr < N) h[(size_t)gr * H + c] = acc[r] + bb;
    }
}

// ---------------------------------------------------------------------------
// CSR build
__global__ __launch_bounds__(256) void hist_kernel(
    const int* __restrict__ dst, int* __restrict__ deg, int E)
{
    int e = blockIdx.x * 256 + threadIdx.x;
    if (e < E) atomicAdd(&deg[dst[e]], 1);
}

// block partial sums: each block covers 2048 elements (8/thread)
__global__ __launch_bounds__(256) void scan_partial_kernel(
    const int* __restrict__ deg, int* __restrict__ bsum, int N)
{
    __shared__ int red[256];
    int b = blockIdx.x, t = threadIdx.x;
    int base = b * 2048 + t * 8;
    int s = 0;
#pragma unroll
    for (int i = 0; i < 8; ++i) { int idx = base + i; if (idx < N) s += deg[idx]; }
    red[t] = s;
    __syncthreads();
    for (int d = 128; d > 0; d >>= 1) {
        if (t < d) red[t] += red[t + d];
        __syncthreads();
    }
    if (t == 0) bsum[b] = red[0];
}

// single block: exclusive-scan the (<=256) block sums; total -> *total
__global__ __launch_bounds__(256) void scan_bsum_kernel(
    int* __restrict__ bsum, int* __restrict__ total, int numB)
{
    __shared__ int ts[256];
    int t = threadIdx.x;
    int v = (t < numB) ? bsum[t] : 0;
    ts[t] = v;
    __syncthreads();
    for (int d = 1; d < 256; d <<= 1) {
        int u = (t >= d) ? ts[t - d] : 0;
        __syncthreads();
        ts[t] += u;
        __syncthreads();
    }
    if (t < numB) bsum[t] = ts[t] - v;   // exclusive
    if (t == 255) *total = ts[255];
}

// apply: offp[i] (and cursor[i]) = global exclusive prefix
__global__ __launch_bounds__(256) void scan_apply_kernel(
    const int* __restrict__ deg, const int* __restrict__ bsum,
    int* __restrict__ offp, int* __restrict__ cursor, int N)
{
    __shared__ int ts[256];
    int b = blockIdx.x, t = threadIdx.x;
    int base = b * 2048 + t * 8;
    int loc[8];
    int s = 0;
#pragma unroll
    for (int i = 0; i < 8; ++i) {
        int idx = base + i;
        loc[i] = (idx < N) ? deg[idx] : 0;
        s += loc[i];
    }
    ts[t] = s;
    __syncthreads();
    for (int d = 1; d < 256; d <<= 1) {
        int u = (t >= d) ? ts[t - d] : 0;
        __syncthreads();
        ts[t] += u;
        __syncthreads();
    }
    int run = bsum[b] + ts[t] - s;       // exclusive start for this thread
#pragma unroll
    for (int i = 0; i < 8; ++i) {
        int idx = base + i;
        if (idx < N) { offp[idx] = run; cursor[idx] = run; }
        run += loc[i];
    }
}

__global__ __launch_bounds__(256) void fill_kernel(
    const int* __restrict__ src, const int* __restrict__ dst,
    int* __restrict__ cursor, int* __restrict__ srclist, int E)
{
    int e = blockIdx.x * 256 + threadIdx.x;
    if (e < E) {
        int pos = atomicAdd(&cursor[dst[e]], 1);
        srclist[pos] = src[e];
    }
}

// ---------------------------------------------------------------------------
// out[v] = f(hin[v]) + sum_{neighbors} f(hin[src]);  f = BN?relu(v*sc+sh):v
// 32 lanes per node, float4/lane
template <int BN>
__global__ __launch_bounds__(256) void gather_kernel(
    const float* __restrict__ hin, const float* __restrict__ ss,
    const int* __restrict__ offp, const int* __restrict__ srclist,
    float* __restrict__ out, int N)
{
    int gid = blockIdx.x * 256 + threadIdx.x;
    int v = gid >> 5;
    if (v >= N) return;
    int c4 = (gid & 31) * 4;
    float4 sc, sh;
    if (BN) {
        sc = *(const float4*)&ss[c4];
        sh = *(const float4*)&ss[H + c4];
    }
    float4 acc = *(const float4*)&hin[(size_t)v * H + c4];
    if (BN) {
        acc.x = fmaxf(acc.x * sc.x + sh.x, 0.f);
        acc.y = fmaxf(acc.y * sc.y + sh.y, 0.f);
        acc.z = fmaxf(acc.z * sc.z + sh.z, 0.f);
        acc.w = fmaxf(acc.w * sc.w + sh.w, 0.f);
    }
    int i0 = offp[v], i1 = offp[v + 1];
    for (int i = i0; i < i1; ++i) {
        int s = srclist[i];
        float4 u = *(const float4*)&hin[(size_t)s * H + c4];
        if (BN) {
            u.x = fmaxf(u.x * sc.x + sh.x, 0.f);
            u.y = fmaxf(u.y * sc.y + sh.y, 0.f);
            u.z = fmaxf(u.z * sc.z + sh.z, 0.f);
            u.w = fmaxf(u.w * sc.w + sh.w, 0.f);
        }
        acc.x += u.x; acc.y += u.y; acc.z += u.z; acc.w += u.w;
    }
    *(float4*)&out[(size_t)v * H + c4] = acc;
}

// ---------------------------------------------------------------------------
// MFMA MLP: z <- relu(z@W1+b1)@W2+b2 (pre-BN, in-place), BN partial stats.
// 256 threads = 4 waves; 32 rows/wave, 128 rows/block.
__global__ __launch_bounds__(256) void mlp_mfma_kernel(
    float* __restrict__ z, const __bf16* __restrict__ W1t,
    const float* __restrict__ b1l, const __bf16* __restrict__ W2t,
    const float* __restrict__ b2l, float* __restrict__ stats, int N)
{
    __shared__ __bf16 hid[4][32 * HS];   // 67.6 KB
    __shared__ float sstat[2 * H];

    int t = threadIdx.x;
    int w = t >> 6, lane = t & 63;
    int l15 = lane & 15, kg = lane >> 4;
    int rbase = blockIdx.x * 128 + w * 32;

    sstat[t] = 0.f;   // 2*H == 256 == blockDim

    // ---- A fragments from z (fp32 -> bf16), two 16-row sets ----
    bf16x8 a[2][4];
#pragma unroll
    for (int s = 0; s < 2; ++s) {
        int r = rbase + s * 16 + l15;
        bool rok = (r < N);
        const float* zrow = z + (size_t)r * H;
#pragma unroll
        for (int kk = 0; kk < 4; ++kk) {
            float4 v0 = make_float4(0.f, 0.f, 0.f, 0.f), v1 = v0;
            if (rok) {
                v0 = *(const float4*)&zrow[kk * 32 + kg * 8];
                v1 = *(const float4*)&zrow[kk * 32 + kg * 8 + 4];
            }
            a[s][kk][0] = (__bf16)v0.x; a[s][kk][1] = (__bf16)v0.y;
            a[s][kk][2] = (__bf16)v0.z; a[s][kk][3] = (__bf16)v0.w;
            a[s][kk][4] = (__bf16)v1.x; a[s][kk][5] = (__bf16)v1.y;
            a[s][kk][6] = (__bf16)v1.z; a[s][kk][7] = (__bf16)v1.w;
        }
    }

    __bf16* hw = &hid[w][0];

    // ---- GEMM1: hid = relu(z @ W1 + b1) ----
#pragma unroll
    for (int nt = 0; nt < 16; ++nt) {
        f32x4 acc0 = {0.f, 0.f, 0.f, 0.f}, acc1 = {0.f, 0.f, 0.f, 0.f};
        int c = nt * 16 + l15;
        const __bf16* bp = W1t + (size_t)c * H + kg * 8;
#pragma unroll
        for (int kk = 0; kk < 4; ++kk) {
            bf16x8 b = *(const bf16x8*)(bp + kk * 32);
            acc0 = __builtin_amdgcn_mfma_f32_16x16x32_bf16(a[0][kk], b, acc0, 0, 0, 0);
            acc1 = __builtin_amdgcn_mfma_f32_16x16x32_bf16(a[1][kk], b, acc1, 0, 0, 0);
        }
        float bb = b1l[c];
#pragma unroll
        for (int q = 0; q < 4; ++q) {
            hw[(kg * 4 + q) * HS + c]      = (__bf16)fmaxf(acc0[q] + bb, 0.f);
            hw[(16 + kg * 4 + q) * HS + c] = (__bf16)fmaxf(acc1[q] + bb, 0.f);
        }
    }
    __syncthreads();

    // ---- A2 fragments from LDS ----
    bf16x8 a2[2][8];
#pragma unroll
    for (int s = 0; s < 2; ++s)
#pragma unroll
        for (int kk = 0; kk < 8; ++kk)
            a2[s][kk] = *(const bf16x8*)&hw[(s * 16 + l15) * HS + kk * 32 + kg * 8];

    // ---- GEMM2 + epilogue ----
#pragma unroll
    for (int nt = 0; nt < 8; ++nt) {
        f32x4 acc0 = {0.f, 0.f, 0.f, 0.f}, acc1 = {0.f, 0.f, 0.f, 0.f};
        int c = nt * 16 + l15;
        const __bf16* bp = W2t + (size_t)c * H2 + kg * 8;
#pragma unroll
        for (int kk = 0; kk < 8; ++kk) {
            bf16x8 b = *(const bf16x8*)(bp + kk * 32);
            acc0 = __builtin_amdgcn_mfma_f32_16x16x32_bf16(a2[0][kk], b, acc0, 0, 0, 0);
            acc1 = __builtin_amdgcn_mfma_f32_16x16x32_bf16(a2[1][kk], b, acc1, 0, 0, 0);
        }
        float bb = b2l[c];
        float ps = 0.f, pq = 0.f;
#pragma unroll
        for (int q = 0; q < 4; ++q) {
            int row = rbase + kg * 4 + q;
            if (row < N) {
                float v = acc0[q] + bb;
                z[(size_t)row * H + c] = v;
                ps += v; pq += v * v;
            }
            int row2 = rbase + 16 + kg * 4 + q;
            if (row2 < N) {
                float v = acc1[q] + bb;
                z[(size_t)row2 * H + c] = v;
                ps += v; pq += v * v;
            }
        }
        ps += __shfl_xor(ps, 16); ps += __shfl_xor(ps, 32);
        pq += __shfl_xor(pq, 16); pq += __shfl_xor(pq, 32);
        if (kg == 0) {
            atomicAdd(&sstat[c], ps);
            atomicAdd(&sstat[H + c], pq);
        }
    }
    __syncthreads();
    atomicAdd(&stats[t], sstat[t]);
}

// ---------------------------------------------------------------------------
__global__ void bn_finalize_kernel(const float* __restrict__ stats,
                                   const float* __restrict__ gamma,
                                   const float* __restrict__ beta,
                                   float* __restrict__ ss, int N)
{
    int j = threadIdx.x;
    float invN = 1.0f / (float)N;
    float mean = stats[j] * invN;
    float var = stats[H + j] * invN - mean * mean;
    float sc = gamma[j] * rsqrtf(var + BN_EPS);
    ss[j] = sc;
    ss[H + j] = beta[j] - mean * sc;
}

// ---------------------------------------------------------------------------
// dst = relu(src*scale + shift)  (src may equal dst)
__global__ __launch_bounds__(256) void bn_apply_kernel(
    const float* __restrict__ src, const float* __restrict__ ss,
    float* __restrict__ dst, int N)
{
    size_t i = (size_t)blockIdx.x * 256 + threadIdx.x;
    size_t total = (size_t)N * (H / 4);
    if (i >= total) return;
    int c4 = (int)(i & (H / 4 - 1));
    float4 v = ((const float4*)src)[i];
    float4 sc = *(const float4*)&ss[c4 * 4];
    float4 sh = *(const float4*)&ss[H + c4 * 4];
    float4 r;
    r.x = fmaxf(v.x * sc.x + sh.x, 0.f);
    r.y = fmaxf(v.y * sc.y + sh.y, 0.f);
    r.z = fmaxf(v.z * sc.z + sh.z, 0.f);
    r.w = fmaxf(v.w * sc.w + sh.w, 0.f);
    ((float4*)dst)[i] = r;
}

// ---------------------------------------------------------------------------
static inline char* align_up(char* p, size_t a) {
    return (char*)(((uintptr_t)p + a - 1) & ~(uintptr_t)(a - 1));
}

extern "C" void kernel_launch(void* const* d_in, const int* in_sizes, int n_in,
                              void* d_out, int out_size, void* d_ws, size_t ws_size,
                              hipStream_t stream)
{
    const float* x    = (const float*)d_in[0];
    const int*   ei   = (const int*)d_in[1];
    const float* embW = (const float*)d_in[2];
    const float* embb = (const float*)d_in[3];
    const float* W1   = (const float*)d_in[4];
    const float* b1   = (const float*)d_in[5];
    const float* W2   = (const float*)d_in[6];
    const float* b2   = (const float*)d_in[7];
    const float* gamma= (const float*)d_in[8];
    const float* beta = (const float*)d_in[9];

    int N = in_sizes[0] / NODE_IN;
    int E = in_sizes[1] / 2;
    int L = in_sizes[4] / (H * H2);
    const int* src = ei;
    const int* dst = ei + E;

    int numB = (N + 2047) / 2048;

    char* w = (char*)d_ws;
    float* z = (float*)w;        w += (size_t)N * H * sizeof(float);
    w = align_up(w, 256);
    float* statsAll = (float*)w; w += (size_t)L * 2 * H * sizeof(float);
    float* ss = (float*)w;       w += 2 * H * sizeof(float);
    int* deg = (int*)w;          w += (size_t)N * sizeof(int);
    int* offp = (int*)w;         w += (size_t)(N + 1) * sizeof(int);
    int* cursor = (int*)w;       w += (size_t)N * sizeof(int);
    int* bsum = (int*)w;         w += (size_t)numB * sizeof(int);
    int* srcl = (int*)w;         w += (size_t)E * sizeof(int);
    w = align_up(w, 256);
    __bf16* W1t = (__bf16*)w;    w += (size_t)L * H * H2 * sizeof(__bf16);
    w = align_up(w, 256);
    __bf16* W2t = (__bf16*)w;    w += (size_t)L * H * H2 * sizeof(__bf16);

    float* hbuf = (float*)d_out;
    float* buf[2] = {hbuf, z};

    // ---- once-per-launch prep ----
    int wtotal2 = 2 * L * H * H2;
    convert_weights_kernel<<<(wtotal2 + 255) / 256, 256, 0, stream>>>(W1, W2, W1t, W2t, L);
    embed_kernel<<<(N + 15) / 16, 256, 0, stream>>>(x, embW, embb, hbuf, N);

    hipMemsetAsync(deg, 0, (size_t)N * sizeof(int), stream);
    hipMemsetAsync(statsAll, 0, (size_t)L * 2 * H * sizeof(float), stream);

    hist_kernel<<<(E + 255) / 256, 256, 0, stream>>>(dst, deg, E);
    scan_partial_kernel<<<numB, 256, 0, stream>>>(deg, bsum, N);
    scan_bsum_kernel<<<1, 256, 0, stream>>>(bsum, offp + N, numB);
    scan_apply_kernel<<<numB, 256, 0, stream>>>(deg, bsum, offp, cursor, N);
    fill_kernel<<<(E + 255) / 256, 256, 0, stream>>>(src, dst, cursor, srcl, E);

    int ggrid = (N * 32 + 255) / 256;
    int mgrid = (N + 127) / 128;
    int agrid = (int)(((size_t)N * (H / 4) + 255) / 256);

    for (int l = 0; l < L; ++l) {
        const float* in = buf[l & 1];
        float* out = buf[(l + 1) & 1];
        if (l == 0)
            gather_kernel<0><<<ggrid, 256, 0, stream>>>(in, nullptr, offp, srcl, out, N);
        else
            gather_kernel<1><<<ggrid, 256, 0, stream>>>(in, ss, offp, srcl, out, N);
        mlp_mfma_kernel<<<mgrid, 256, 0, stream>>>(
            out, W1t + (size_t)l * H * H2, b1 + (size_t)l * H2,
            W2t + (size_t)l * H * H2, b2 + (size_t)l * H,
            statsAll + (size_t)l * 2 * H, N);
        bn_finalize_kernel<<<1, H, 0, stream>>>(
            statsAll + (size_t)l * 2 * H, gamma + (size_t)l * H, beta + (size_t)l * H, ss, N);
    }
    // final: h = relu(BN(z_final)); buffer holding final pre-BN is buf[L&1]
    bn_apply_kernel<<<agrid, 256, 0, stream>>>(buf[L & 1], ss, hbuf, N);
}

// Round 4
// 621.435 us; speedup vs baseline: 8.8116x; 1.0694x over previous
//
#include <hip/hip_runtime.h>

#define H 128
#define H2 256
#define NODE_IN 32
#define BN_EPS 1e-5f

typedef __bf16 bf16x8 __attribute__((ext_vector_type(8)));
typedef __bf16 bf16x4 __attribute__((ext_vector_type(4)));
typedef float f32x4 __attribute__((ext_vector_type(4)));

#define HS 264  // hid LDS row stride in bf16 (528 B: bank offset 4 per row -> 2-way max)

// ---------------------------------------------------------------------------
// W1 [L][128][256] -> W1t [L][256][128] bf16 ; W2 [L][256][128] -> W2t [L][128][256] bf16
__global__ __launch_bounds__(256) void convert_weights_kernel(
    const float* __restrict__ W1, const float* __restrict__ W2,
    __bf16* __restrict__ W1t, __bf16* __restrict__ W2t, int L)
{
    int idx = blockIdx.x * 256 + threadIdx.x;
    int per = H * H2;
    int total = L * per;
    if (idx < total) {
        int l = idx / per, r = idx % per;
        int k = r / H2, n = r % H2;
        W1t[(size_t)l * per + (size_t)n * H + k] = (__bf16)W1[idx];
    } else if (idx < 2 * total) {
        int j = idx - total;
        int l = j / per, r = j % per;
        int k = r / H, n = r % H;
        W2t[(size_t)l * per + (size_t)n * H2 + k] = (__bf16)W2[j];
    }
}

// ---------------------------------------------------------------------------
__global__ __launch_bounds__(256) void embed_kernel(
    const float* __restrict__ x, const float* __restrict__ W,
    const float* __restrict__ bias, float* __restrict__ h, int N)
{
    __shared__ float xs[16][NODE_IN + 4];
    int row0 = blockIdx.x * 16;
    int t = threadIdx.x;
    if (t < 128) {
        int r = t >> 3, c4 = t & 7;
        int gr = row0 + r;
        float4 v = make_float4(0.f, 0.f, 0.f, 0.f);
        if (gr < N) v = *(const float4*)&x[(size_t)gr * NODE_IN + c4 * 4];
        *(float4*)&xs[r][c4 * 4] = v;
    }
    __syncthreads();
    int c = t & (H - 1);
    int rg = t >> 7;
    int r0 = rg * 8;
    float acc[8] = {0, 0, 0, 0, 0, 0, 0, 0};
    for (int k = 0; k < NODE_IN; ++k) {
        float w = W[k * H + c];
#pragma unroll
        for (int r = 0; r < 8; ++r) acc[r] += xs[r0 + r][k] * w;
    }
    float bb = bias[c];
#pragma unroll
    for (int r = 0; r < 8; ++r) {
        int gr = row0 + r0 + r;
        if (gr < N) h[(size_t)gr * H + c] = acc[r] + bb;
    }
}

// ---------------------------------------------------------------------------
// CSR build
__global__ __launch_bounds__(256) void hist_kernel(
    const int* __restrict__ dst, int* __restrict__ deg, int E)
{
    int e = blockIdx.x * 256 + threadIdx.x;
    if (e < E) atomicAdd(&deg[dst[e]], 1);
}

__global__ __launch_bounds__(256) void scan_partial_kernel(
    const int* __restrict__ deg, int* __restrict__ bsum, int N)
{
    __shared__ int red[256];
    int b = blockIdx.x, t = threadIdx.x;
    int base = b * 2048 + t * 8;
    int s = 0;
#pragma unroll
    for (int i = 0; i < 8; ++i) { int idx = base + i; if (idx < N) s += deg[idx]; }
    red[t] = s;
    __syncthreads();
    for (int d = 128; d > 0; d >>= 1) {
        if (t < d) red[t] += red[t + d];
        __syncthreads();
    }
    if (t == 0) bsum[b] = red[0];
}

__global__ __launch_bounds__(256) void scan_bsum_kernel(
    int* __restrict__ bsum, int* __restrict__ total, int numB)
{
    __shared__ int ts[256];
    int t = threadIdx.x;
    int v = (t < numB) ? bsum[t] : 0;
    ts[t] = v;
    __syncthreads();
    for (int d = 1; d < 256; d <<= 1) {
        int u = (t >= d) ? ts[t - d] : 0;
        __syncthreads();
        ts[t] += u;
        __syncthreads();
    }
    if (t < numB) bsum[t] = ts[t] - v;
    if (t == 255) *total = ts[255];
}

__global__ __launch_bounds__(256) void scan_apply_kernel(
    const int* __restrict__ deg, const int* __restrict__ bsum,
    int* __restrict__ offp, int* __restrict__ cursor, int N)
{
    __shared__ int ts[256];
    int b = blockIdx.x, t = threadIdx.x;
    int base = b * 2048 + t * 8;
    int loc[8];
    int s = 0;
#pragma unroll
    for (int i = 0; i < 8; ++i) {
        int idx = base + i;
        loc[i] = (idx < N) ? deg[idx] : 0;
        s += loc[i];
    }
    ts[t] = s;
    __syncthreads();
    for (int d = 1; d < 256; d <<= 1) {
        int u = (t >= d) ? ts[t - d] : 0;
        __syncthreads();
        ts[t] += u;
        __syncthreads();
    }
    int run = bsum[b] + ts[t] - s;
#pragma unroll
    for (int i = 0; i < 8; ++i) {
        int idx = base + i;
        if (idx < N) { offp[idx] = run; cursor[idx] = run; }
        run += loc[i];
    }
}

__global__ __launch_bounds__(256) void fill_kernel(
    const int* __restrict__ src, const int* __restrict__ dst,
    int* __restrict__ cursor, int* __restrict__ srclist, int E)
{
    int e = blockIdx.x * 256 + threadIdx.x;
    if (e < E) {
        int pos = atomicAdd(&cursor[dst[e]], 1);
        srclist[pos] = src[e];
    }
}

// ---------------------------------------------------------------------------
// zg[v] = bf16( f(hin[v]) + sum_{nbr} f(hin[src]) );  f = BN?relu(v*sc+sh):v
// 32 lanes per node, float4/lane; neighbor loop unrolled x2
template <int BN>
__global__ __launch_bounds__(256) void gather_kernel(
    const float* __restrict__ hin, const float* __restrict__ ss,
    const int* __restrict__ offp, const int* __restrict__ srclist,
    __bf16* __restrict__ zg, int N)
{
    int gid = blockIdx.x * 256 + threadIdx.x;
    int v = gid >> 5;
    if (v >= N) return;
    int c4 = (gid & 31) * 4;
    float4 sc, sh;
    if (BN) {
        sc = *(const float4*)&ss[c4];
        sh = *(const float4*)&ss[H + c4];
    }
    float4 acc = *(const float4*)&hin[(size_t)v * H + c4];
    if (BN) {
        acc.x = fmaxf(acc.x * sc.x + sh.x, 0.f);
        acc.y = fmaxf(acc.y * sc.y + sh.y, 0.f);
        acc.z = fmaxf(acc.z * sc.z + sh.z, 0.f);
        acc.w = fmaxf(acc.w * sc.w + sh.w, 0.f);
    }
    int i0 = offp[v], i1 = offp[v + 1];
    int i = i0;
    for (; i + 1 < i1; i += 2) {
        int s0 = srclist[i], s1 = srclist[i + 1];
        float4 u0 = *(const float4*)&hin[(size_t)s0 * H + c4];
        float4 u1 = *(const float4*)&hin[(size_t)s1 * H + c4];
        if (BN) {
            u0.x = fmaxf(u0.x * sc.x + sh.x, 0.f);
            u0.y = fmaxf(u0.y * sc.y + sh.y, 0.f);
            u0.z = fmaxf(u0.z * sc.z + sh.z, 0.f);
            u0.w = fmaxf(u0.w * sc.w + sh.w, 0.f);
            u1.x = fmaxf(u1.x * sc.x + sh.x, 0.f);
            u1.y = fmaxf(u1.y * sc.y + sh.y, 0.f);
            u1.z = fmaxf(u1.z * sc.z + sh.z, 0.f);
            u1.w = fmaxf(u1.w * sc.w + sh.w, 0.f);
        }
        acc.x += u0.x + u1.x; acc.y += u0.y + u1.y;
        acc.z += u0.z + u1.z; acc.w += u0.w + u1.w;
    }
    if (i < i1) {
        int s0 = srclist[i];
        float4 u0 = *(const float4*)&hin[(size_t)s0 * H + c4];
        if (BN) {
            u0.x = fmaxf(u0.x * sc.x + sh.x, 0.f);
            u0.y = fmaxf(u0.y * sc.y + sh.y, 0.f);
            u0.z = fmaxf(u0.z * sc.z + sh.z, 0.f);
            u0.w = fmaxf(u0.w * sc.w + sh.w, 0.f);
        }
        acc.x += u0.x; acc.y += u0.y; acc.z += u0.z; acc.w += u0.w;
    }
    bf16x4 o = {(__bf16)acc.x, (__bf16)acc.y, (__bf16)acc.z, (__bf16)acc.w};
    *(bf16x4*)&zg[(size_t)v * H + c4] = o;
}

// ---------------------------------------------------------------------------
// MFMA MLP: zp = relu(zg@W1+b1)@W2+b2 (pre-BN); per-wave BN partial stats
// stored (no atomics). 256 threads = 4 waves; 32 rows/wave, 128 rows/block.
// No block barriers: hid is per-wave LDS (lgkmcnt-ordered within a wave).
__global__ __launch_bounds__(256, 2) void mlp_mfma_kernel(
    const __bf16* __restrict__ zg, float* __restrict__ zp,
    const __bf16* __restrict__ W1t, const float* __restrict__ b1l,
    const __bf16* __restrict__ W2t, const float* __restrict__ b2l,
    float* __restrict__ spart, int N)
{
    __shared__ __bf16 hid[4][32 * HS];   // 67.6 KB

    int t = threadIdx.x;
    int w = t >> 6, lane = t & 63;
    int l15 = lane & 15, kg = lane >> 4;
    int rbase = blockIdx.x * 128 + w * 32;

    // ---- A fragments (bf16 direct) ----
    bf16x8 a[2][4];
#pragma unroll
    for (int s = 0; s < 2; ++s) {
        int r = rbase + s * 16 + l15;
        const __bf16* zrow = zg + (size_t)r * H;
        if (r < N) {
#pragma unroll
            for (int kk = 0; kk < 4; ++kk)
                a[s][kk] = *(const bf16x8*)(zrow + kk * 32 + kg * 8);
        } else {
#pragma unroll
            for (int kk = 0; kk < 4; ++kk) {
#pragma unroll
                for (int e = 0; e < 8; ++e) a[s][kk][e] = (__bf16)0.f;
            }
        }
    }

    // ---- bias preload ----
    float bb1[16], bb2[8];
#pragma unroll
    for (int nt = 0; nt < 16; ++nt) bb1[nt] = b1l[nt * 16 + l15];
#pragma unroll
    for (int nt = 0; nt < 8; ++nt)  bb2[nt] = b2l[nt * 16 + l15];

    __bf16* hw = &hid[w][0];

#define LD1(nt, kk) (*(const bf16x8*)(W1t + (size_t)((nt) * 16 + l15) * H + (kk) * 32 + kg * 8))
#define LD2(nt, kk) (*(const bf16x8*)(W2t + (size_t)((nt) * 16 + l15) * H2 + (kk) * 32 + kg * 8))

    // ---- GEMM1: hid = relu(zg @ W1 + b1), B double-buffered ----
    bf16x8 c0 = LD1(0, 0), c1 = LD1(0, 1), c2 = LD1(0, 2), c3 = LD1(0, 3);
#pragma unroll
    for (int nt = 0; nt < 16; ++nt) {
        bf16x8 n0, n1, n2, n3;
        if (nt < 15) { n0 = LD1(nt + 1, 0); n1 = LD1(nt + 1, 1); n2 = LD1(nt + 1, 2); n3 = LD1(nt + 1, 3); }
        f32x4 acc0 = {0.f, 0.f, 0.f, 0.f}, acc1 = {0.f, 0.f, 0.f, 0.f};
        acc0 = __builtin_amdgcn_mfma_f32_16x16x32_bf16(a[0][0], c0, acc0, 0, 0, 0);
        acc1 = __builtin_amdgcn_mfma_f32_16x16x32_bf16(a[1][0], c0, acc1, 0, 0, 0);
        acc0 = __builtin_amdgcn_mfma_f32_16x16x32_bf16(a[0][1], c1, acc0, 0, 0, 0);
        acc1 = __builtin_amdgcn_mfma_f32_16x16x32_bf16(a[1][1], c1, acc1, 0, 0, 0);
        acc0 = __builtin_amdgcn_mfma_f32_16x16x32_bf16(a[0][2], c2, acc0, 0, 0, 0);
        acc1 = __builtin_amdgcn_mfma_f32_16x16x32_bf16(a[1][2], c2, acc1, 0, 0, 0);
        acc0 = __builtin_amdgcn_mfma_f32_16x16x32_bf16(a[0][3], c3, acc0, 0, 0, 0);
        acc1 = __builtin_amdgcn_mfma_f32_16x16x32_bf16(a[1][3], c3, acc1, 0, 0, 0);
        int c = nt * 16 + l15;
        float bb = bb1[nt];
#pragma unroll
        for (int q = 0; q < 4; ++q) {
            hw[(kg * 4 + q) * HS + c]      = (__bf16)fmaxf(acc0[q] + bb, 0.f);
            hw[(16 + kg * 4 + q) * HS + c] = (__bf16)fmaxf(acc1[q] + bb, 0.f);
        }
        c0 = n0; c1 = n1; c2 = n2; c3 = n3;
    }

    // ---- A2 fragments from per-wave LDS (no barrier needed) ----
    bf16x8 a2[2][8];
#pragma unroll
    for (int s = 0; s < 2; ++s)
#pragma unroll
        for (int kk = 0; kk < 8; ++kk)
            a2[s][kk] = *(const bf16x8*)&hw[(s * 16 + l15) * HS + kk * 32 + kg * 8];

    // ---- GEMM2 + epilogue, B double-buffered ----
    bf16x8 d0 = LD2(0, 0), d1 = LD2(0, 1), d2 = LD2(0, 2), d3 = LD2(0, 3);
    bf16x8 d4 = LD2(0, 4), d5 = LD2(0, 5), d6 = LD2(0, 6), d7 = LD2(0, 7);
#pragma unroll
    for (int nt = 0; nt < 8; ++nt) {
        bf16x8 e0, e1, e2, e3, e4, e5, e6, e7;
        if (nt < 7) {
            e0 = LD2(nt + 1, 0); e1 = LD2(nt + 1, 1); e2 = LD2(nt + 1, 2); e3 = LD2(nt + 1, 3);
            e4 = LD2(nt + 1, 4); e5 = LD2(nt + 1, 5); e6 = LD2(nt + 1, 6); e7 = LD2(nt + 1, 7);
        }
        f32x4 acc0 = {0.f, 0.f, 0.f, 0.f}, acc1 = {0.f, 0.f, 0.f, 0.f};
        acc0 = __builtin_amdgcn_mfma_f32_16x16x32_bf16(a2[0][0], d0, acc0, 0, 0, 0);
        acc1 = __builtin_amdgcn_mfma_f32_16x16x32_bf16(a2[1][0], d0, acc1, 0, 0, 0);
        acc0 = __builtin_amdgcn_mfma_f32_16x16x32_bf16(a2[0][1], d1, acc0, 0, 0, 0);
        acc1 = __builtin_amdgcn_mfma_f32_16x16x32_bf16(a2[1][1], d1, acc1, 0, 0, 0);
        acc0 = __builtin_amdgcn_mfma_f32_16x16x32_bf16(a2[0][2], d2, acc0, 0, 0, 0);
        acc1 = __builtin_amdgcn_mfma_f32_16x16x32_bf16(a2[1][2], d2, acc1, 0, 0, 0);
        acc0 = __builtin_amdgcn_mfma_f32_16x16x32_bf16(a2[0][3], d3, acc0, 0, 0, 0);
        acc1 = __builtin_amdgcn_mfma_f32_16x16x32_bf16(a2[1][3], d3, acc1, 0, 0, 0);
        acc0 = __builtin_amdgcn_mfma_f32_16x16x32_bf16(a2[0][4], d4, acc0, 0, 0, 0);
        acc1 = __builtin_amdgcn_mfma_f32_16x16x32_bf16(a2[1][4], d4, acc1, 0, 0, 0);
        acc0 = __builtin_amdgcn_mfma_f32_16x16x32_bf16(a2[0][5], d5, acc0, 0, 0, 0);
        acc1 = __builtin_amdgcn_mfma_f32_16x16x32_bf16(a2[1][5], d5, acc1, 0, 0, 0);
        acc0 = __builtin_amdgcn_mfma_f32_16x16x32_bf16(a2[0][6], d6, acc0, 0, 0, 0);
        acc1 = __builtin_amdgcn_mfma_f32_16x16x32_bf16(a2[1][6], d6, acc1, 0, 0, 0);
        acc0 = __builtin_amdgcn_mfma_f32_16x16x32_bf16(a2[0][7], d7, acc0, 0, 0, 0);
        acc1 = __builtin_amdgcn_mfma_f32_16x16x32_bf16(a2[1][7], d7, acc1, 0, 0, 0);

        int c = nt * 16 + l15;
        float bb = bb2[nt];
        float ps = 0.f, pq = 0.f;
#pragma unroll
        for (int q = 0; q < 4; ++q) {
            int row = rbase + kg * 4 + q;
            if (row < N) {
                float v = acc0[q] + bb;
                zp[(size_t)row * H + c] = v;
                ps += v; pq += v * v;
            }
            int row2 = rbase + 16 + kg * 4 + q;
            if (row2 < N) {
                float v = acc1[q] + bb;
                zp[(size_t)row2 * H + c] = v;
                ps += v; pq += v * v;
            }
        }
        ps += __shfl_xor(ps, 16); ps += __shfl_xor(ps, 32);
        pq += __shfl_xor(pq, 16); pq += __shfl_xor(pq, 32);
        if (kg == 0) {
            size_t rp = (size_t)(blockIdx.x * 4 + w) * 256;
            spart[rp + c] = ps;
            spart[rp + 128 + c] = pq;
        }
        d0 = e0; d1 = e1; d2 = e2; d3 = e3;
        d4 = e4; d5 = e5; d6 = e6; d7 = e7;
    }
#undef LD1
#undef LD2
}

// ---------------------------------------------------------------------------
// stats[t] += sum over partial rows (t in [0,256): 0..127 = sum, 128..255 = sqsum)
__global__ __launch_bounds__(256) void reduce_stats_kernel(
    const float* __restrict__ spart, float* __restrict__ stats, int R)
{
    int t = threadIdx.x;
    int b = blockIdx.x;
    int per = (R + gridDim.x - 1) / gridDim.x;
    int r0 = b * per, r1 = r0 + per;
    if (r1 > R) r1 = R;
    float s = 0.f;
    for (int r = r0; r < r1; ++r) s += spart[(size_t)r * 256 + t];
    atomicAdd(&stats[t], s);
}

// ---------------------------------------------------------------------------
__global__ void bn_finalize_kernel(const float* __restrict__ stats,
                                   const float* __restrict__ gamma,
                                   const float* __restrict__ beta,
                                   float* __restrict__ ss, int N)
{
    int j = threadIdx.x;
    float invN = 1.0f / (float)N;
    float mean = stats[j] * invN;
    float var = stats[H + j] * invN - mean * mean;
    float sc = gamma[j] * rsqrtf(var + BN_EPS);
    ss[j] = sc;
    ss[H + j] = beta[j] - mean * sc;
}

// ---------------------------------------------------------------------------
__global__ __launch_bounds__(256) void bn_apply_kernel(
    const float* __restrict__ src, const float* __restrict__ ss,
    float* __restrict__ dstp, int N)
{
    size_t i = (size_t)blockIdx.x * 256 + threadIdx.x;
    size_t total = (size_t)N * (H / 4);
    if (i >= total) return;
    int c4 = (int)(i & (H / 4 - 1));
    float4 v = ((const float4*)src)[i];
    float4 sc = *(const float4*)&ss[c4 * 4];
    float4 sh = *(const float4*)&ss[H + c4 * 4];
    float4 r;
    r.x = fmaxf(v.x * sc.x + sh.x, 0.f);
    r.y = fmaxf(v.y * sc.y + sh.y, 0.f);
    r.z = fmaxf(v.z * sc.z + sh.z, 0.f);
    r.w = fmaxf(v.w * sc.w + sh.w, 0.f);
    ((float4*)dstp)[i] = r;
}

// ---------------------------------------------------------------------------
static inline char* align_up(char* p, size_t a) {
    return (char*)(((uintptr_t)p + a - 1) & ~(uintptr_t)(a - 1));
}

extern "C" void kernel_launch(void* const* d_in, const int* in_sizes, int n_in,
                              void* d_out, int out_size, void* d_ws, size_t ws_size,
                              hipStream_t stream)
{
    const float* x    = (const float*)d_in[0];
    const int*   ei   = (const int*)d_in[1];
    const float* embW = (const float*)d_in[2];
    const float* embb = (const float*)d_in[3];
    const float* W1   = (const float*)d_in[4];
    const float* b1   = (const float*)d_in[5];
    const float* W2   = (const float*)d_in[6];
    const float* b2   = (const float*)d_in[7];
    const float* gamma= (const float*)d_in[8];
    const float* beta = (const float*)d_in[9];

    int N = in_sizes[0] / NODE_IN;
    int E = in_sizes[1] / 2;
    int L = in_sizes[4] / (H * H2);
    const int* src = ei;
    const int* dst = ei + E;

    int numB = (N + 2047) / 2048;
    int mgrid = (N + 127) / 128;
    int Rpart = mgrid * 4;

    char* w = (char*)d_ws;
    float* zp = (float*)w;        w += (size_t)N * H * sizeof(float);
    w = align_up(w, 256);
    __bf16* zg = (__bf16*)w;      w += (size_t)N * H * sizeof(__bf16);
    w = align_up(w, 256);
    float* spart = (float*)w;     w += (size_t)Rpart * 256 * sizeof(float);
    float* statsAll = (float*)w;  w += (size_t)L * 2 * H * sizeof(float);
    float* ss = (float*)w;        w += 2 * H * sizeof(float);
    int* deg = (int*)w;           w += (size_t)N * sizeof(int);
    int* offp = (int*)w;          w += (size_t)(N + 1) * sizeof(int);
    int* cursor = (int*)w;        w += (size_t)N * sizeof(int);
    int* bsum = (int*)w;          w += (size_t)numB * sizeof(int);
    int* srcl = (int*)w;          w += (size_t)E * sizeof(int);
    w = align_up(w, 256);
    __bf16* W1t = (__bf16*)w;     w += (size_t)L * H * H2 * sizeof(__bf16);
    w = align_up(w, 256);
    __bf16* W2t = (__bf16*)w;     w += (size_t)L * H * H2 * sizeof(__bf16);

    float* hbuf = (float*)d_out;

    // ---- once-per-launch prep ----
    int wtotal2 = 2 * L * H * H2;
    convert_weights_kernel<<<(wtotal2 + 255) / 256, 256, 0, stream>>>(W1, W2, W1t, W2t, L);
    embed_kernel<<<(N + 15) / 16, 256, 0, stream>>>(x, embW, embb, hbuf, N);

    hipMemsetAsync(deg, 0, (size_t)N * sizeof(int), stream);
    hipMemsetAsync(statsAll, 0, (size_t)L * 2 * H * sizeof(float), stream);

    hist_kernel<<<(E + 255) / 256, 256, 0, stream>>>(dst, deg, E);
    scan_partial_kernel<<<numB, 256, 0, stream>>>(deg, bsum, N);
    scan_bsum_kernel<<<1, 256, 0, stream>>>(bsum, offp + N, numB);
    scan_apply_kernel<<<numB, 256, 0, stream>>>(deg, bsum, offp, cursor, N);
    fill_kernel<<<(E + 255) / 256, 256, 0, stream>>>(src, dst, cursor, srcl, E);

    int ggrid = (N * 32 + 255) / 256;
    int agrid = (int)(((size_t)N * (H / 4) + 255) / 256);

    for (int l = 0; l < L; ++l) {
        float* stats = statsAll + (size_t)l * 2 * H;
        if (l == 0)
            gather_kernel<0><<<ggrid, 256, 0, stream>>>(hbuf, nullptr, offp, srcl, zg, N);
        else
            gather_kernel<1><<<ggrid, 256, 0, stream>>>(zp, ss, offp, srcl, zg, N);
        mlp_mfma_kernel<<<mgrid, 256, 0, stream>>>(
            zg, zp, W1t + (size_t)l * H * H2, b1 + (size_t)l * H2,
            W2t + (size_t)l * H * H2, b2 + (size_t)l * H, spart, N);
        reduce_stats_kernel<<<64, 256, 0, stream>>>(spart, stats, Rpart);
        bn_finalize_kernel<<<1, H, 0, stream>>>(
            stats, gamma + (size_t)l * H, beta + (size_t)l * H, ss, N);
    }
    bn_apply_kernel<<<agrid, 256, 0, stream>>>(zp, ss, hbuf, N);
}

// Round 5
// 516.952 us; speedup vs baseline: 10.5925x; 1.2021x over previous
//
#include <hip/hip_runtime.h>

#define H 128
#define H2 256
#define NODE_IN 32
#define BN_EPS 1e-5f

typedef __bf16 bf16x8 __attribute__((ext_vector_type(8)));
typedef __bf16 bf16x4 __attribute__((ext_vector_type(4)));
typedef float f32x4 __attribute__((ext_vector_type(4)));

#define MFMA(a, b, c) __builtin_amdgcn_mfma_f32_16x16x32_bf16(a, b, c, 0, 0, 0)

// ---------------------------------------------------------------------------
// W1 [L][128][256] -> W1t [L][256][128] bf16 ; W2 [L][256][128] -> W2t [L][128][256] bf16
__global__ __launch_bounds__(256) void convert_weights_kernel(
    const float* __restrict__ W1, const float* __restrict__ W2,
    __bf16* __restrict__ W1t, __bf16* __restrict__ W2t, int L)
{
    int idx = blockIdx.x * 256 + threadIdx.x;
    int per = H * H2;
    int total = L * per;
    if (idx < total) {
        int l = idx / per, r = idx % per;
        int k = r / H2, n = r % H2;
        W1t[(size_t)l * per + (size_t)n * H + k] = (__bf16)W1[idx];
    } else if (idx < 2 * total) {
        int j = idx - total;
        int l = j / per, r = j % per;
        int k = r / H, n = r % H;
        W2t[(size_t)l * per + (size_t)n * H2 + k] = (__bf16)W2[j];
    }
}

// ---------------------------------------------------------------------------
// h0 = x @ emb_W + emb_b  (bf16 out)
__global__ __launch_bounds__(256) void embed_kernel(
    const float* __restrict__ x, const float* __restrict__ W,
    const float* __restrict__ bias, __bf16* __restrict__ h, int N)
{
    __shared__ float xs[16][NODE_IN + 4];
    int row0 = blockIdx.x * 16;
    int t = threadIdx.x;
    if (t < 128) {
        int r = t >> 3, c4 = t & 7;
        int gr = row0 + r;
        float4 v = make_float4(0.f, 0.f, 0.f, 0.f);
        if (gr < N) v = *(const float4*)&x[(size_t)gr * NODE_IN + c4 * 4];
        *(float4*)&xs[r][c4 * 4] = v;
    }
    __syncthreads();
    int c = t & (H - 1);
    int rg = t >> 7;
    int r0 = rg * 8;
    float acc[8] = {0, 0, 0, 0, 0, 0, 0, 0};
    for (int k = 0; k < NODE_IN; ++k) {
        float w = W[k * H + c];
#pragma unroll
        for (int r = 0; r < 8; ++r) acc[r] += xs[r0 + r][k] * w;
    }
    float bb = bias[c];
#pragma unroll
    for (int r = 0; r < 8; ++r) {
        int gr = row0 + r0 + r;
        if (gr < N) h[(size_t)gr * H + c] = (__bf16)(acc[r] + bb);
    }
}

// ---------------------------------------------------------------------------
// CSR build
__global__ __launch_bounds__(256) void hist_kernel(
    const int* __restrict__ dst, int* __restrict__ deg, int E)
{
    int e = blockIdx.x * 256 + threadIdx.x;
    if (e < E) atomicAdd(&deg[dst[e]], 1);
}

__global__ __launch_bounds__(256) void scan_partial_kernel(
    const int* __restrict__ deg, int* __restrict__ bsum, int N)
{
    __shared__ int red[256];
    int b = blockIdx.x, t = threadIdx.x;
    int base = b * 2048 + t * 8;
    int s = 0;
#pragma unroll
    for (int i = 0; i < 8; ++i) { int idx = base + i; if (idx < N) s += deg[idx]; }
    red[t] = s;
    __syncthreads();
    for (int d = 128; d > 0; d >>= 1) {
        if (t < d) red[t] += red[t + d];
        __syncthreads();
    }
    if (t == 0) bsum[b] = red[0];
}

__global__ __launch_bounds__(256) void scan_bsum_kernel(
    int* __restrict__ bsum, int* __restrict__ total, int numB)
{
    __shared__ int ts[256];
    int t = threadIdx.x;
    int v = (t < numB) ? bsum[t] : 0;
    ts[t] = v;
    __syncthreads();
    for (int d = 1; d < 256; d <<= 1) {
        int u = (t >= d) ? ts[t - d] : 0;
        __syncthreads();
        ts[t] += u;
        __syncthreads();
    }
    if (t < numB) bsum[t] = ts[t] - v;
    if (t == 255) *total = ts[255];
}

__global__ __launch_bounds__(256) void scan_apply_kernel(
    const int* __restrict__ deg, const int* __restrict__ bsum,
    int* __restrict__ offp, int* __restrict__ cursor, int N)
{
    __shared__ int ts[256];
    int b = blockIdx.x, t = threadIdx.x;
    int base = b * 2048 + t * 8;
    int loc[8];
    int s = 0;
#pragma unroll
    for (int i = 0; i < 8; ++i) {
        int idx = base + i;
        loc[i] = (idx < N) ? deg[idx] : 0;
        s += loc[i];
    }
    ts[t] = s;
    __syncthreads();
    for (int d = 1; d < 256; d <<= 1) {
        int u = (t >= d) ? ts[t - d] : 0;
        __syncthreads();
        ts[t] += u;
        __syncthreads();
    }
    int run = bsum[b] + ts[t] - s;
#pragma unroll
    for (int i = 0; i < 8; ++i) {
        int idx = base + i;
        if (idx < N) { offp[idx] = run; cursor[idx] = run; }
        run += loc[i];
    }
}

__global__ __launch_bounds__(256) void fill_kernel(
    const int* __restrict__ src, const int* __restrict__ dst,
    int* __restrict__ cursor, int* __restrict__ srclist, int E)
{
    int e = blockIdx.x * 256 + threadIdx.x;
    if (e < E) {
        int pos = atomicAdd(&cursor[dst[e]], 1);
        srclist[pos] = src[e];
    }
}

// ---------------------------------------------------------------------------
// zg[v] = bf16( f(hin[v]) + sum_{nbr} f(hin[src]) ); f = BN?relu(v*sc+sh):v
// 16 lanes per node, bf16x8 (16B)/lane. Output is 16B-chunk XOR-swizzled:
// chunk' = chunk ^ (row & 7)  (consumed by mlp's LDS reads).
template <int BN>
__global__ __launch_bounds__(256) void gather_kernel(
    const __bf16* __restrict__ hin, const float* __restrict__ ss,
    const int* __restrict__ offp, const int* __restrict__ srclist,
    char* __restrict__ zg, int N)
{
    int gid = blockIdx.x * 256 + threadIdx.x;
    int v = gid >> 4;
    if (v >= N) return;
    int c16 = gid & 15;
    float sc[8], sh[8];
    if (BN) {
#pragma unroll
        for (int j = 0; j < 8; ++j) { sc[j] = ss[c16 * 8 + j]; sh[j] = ss[H + c16 * 8 + j]; }
    }
    float acc[8];
    bf16x8 sv = *(const bf16x8*)(hin + (size_t)v * H + c16 * 8);
#pragma unroll
    for (int j = 0; j < 8; ++j) {
        float f = (float)sv[j];
        acc[j] = BN ? fmaxf(f * sc[j] + sh[j], 0.f) : f;
    }
    int i0 = offp[v], i1 = offp[v + 1];
    int i = i0;
    for (; i + 1 < i1; i += 2) {
        int s0 = srclist[i], s1 = srclist[i + 1];
        bf16x8 u0 = *(const bf16x8*)(hin + (size_t)s0 * H + c16 * 8);
        bf16x8 u1 = *(const bf16x8*)(hin + (size_t)s1 * H + c16 * 8);
#pragma unroll
        for (int j = 0; j < 8; ++j) {
            float f0 = (float)u0[j], f1 = (float)u1[j];
            if (BN) {
                f0 = fmaxf(f0 * sc[j] + sh[j], 0.f);
                f1 = fmaxf(f1 * sc[j] + sh[j], 0.f);
            }
            acc[j] += f0 + f1;
        }
    }
    if (i < i1) {
        int s0 = srclist[i];
        bf16x8 u0 = *(const bf16x8*)(hin + (size_t)s0 * H + c16 * 8);
#pragma unroll
        for (int j = 0; j < 8; ++j) {
            float f0 = (float)u0[j];
            if (BN) f0 = fmaxf(f0 * sc[j] + sh[j], 0.f);
            acc[j] += f0;
        }
    }
    bf16x8 o;
#pragma unroll
    for (int j = 0; j < 8; ++j) o[j] = (__bf16)acc[j];
    int chunk = c16 ^ (v & 7);
    *(bf16x8*)(zg + (size_t)v * 256 + chunk * 16) = o;
}

// ---------------------------------------------------------------------------
// async stage: 512 threads x 16B = one 32-row bf16 tile (8KB) into LDS
__device__ __forceinline__ void stage_tile(const char* zg, int tile, char* dst, int tid)
{
    const char* g = zg + (size_t)tile * 8192 + tid * 16;
    char* l = dst + (tid >> 6) * 1024;  // wave-uniform LDS base; HW adds lane*16
    __builtin_amdgcn_global_load_lds(
        (const __attribute__((address_space(1))) void*)g,
        (__attribute__((address_space(3))) void*)l, 16, 0, 0);
}

// ---------------------------------------------------------------------------
// Persistent-weight MLP. 512 thr = 8 waves. Wave w owns hidden cols
// [w*32,w*32+32) (GEMM1, A=W1t frags in regs) and output cols [w*16,w*16+16)
// (GEMM2, A=W2t frags in regs). B operand = activation rows (swapped MFMA):
// D lane holds 4 consecutive cols of one row -> b64 hid writes / dwordx2 zp
// stores. zg tiles double-buffered in LDS via global_load_lds.
__global__ __launch_bounds__(512, 4) void mlp_mfma_kernel(
    const char* __restrict__ zg, __bf16* __restrict__ zpb,
    const __bf16* __restrict__ W1t, const float* __restrict__ b1l,
    const __bf16* __restrict__ W2t, const float* __restrict__ b2l,
    float* __restrict__ stats, int N, int T, int G)
{
    __shared__ char zt[2][8192];
    __shared__ __bf16 hid[32][264];

    int tid = threadIdx.x;
    int w = tid >> 6, lane = tid & 63;
    int l15 = lane & 15, kg = lane >> 4;

    // ---- persistent weight fragments ----
    bf16x8 aW1[2][4], aW2[8];
#pragma unroll
    for (int nt = 0; nt < 2; ++nt)
#pragma unroll
        for (int kk = 0; kk < 4; ++kk)
            aW1[nt][kk] = *(const bf16x8*)(W1t + (size_t)(w * 32 + nt * 16 + l15) * H + kk * 32 + kg * 8);
#pragma unroll
    for (int kk = 0; kk < 8; ++kk)
        aW2[kk] = *(const bf16x8*)(W2t + (size_t)(w * 16 + l15) * H2 + kk * 32 + kg * 8);

    float bb1[2][4], bb2[4];
#pragma unroll
    for (int nt = 0; nt < 2; ++nt)
#pragma unroll
        for (int q = 0; q < 4; ++q) bb1[nt][q] = b1l[w * 32 + nt * 16 + kg * 4 + q];
#pragma unroll
    for (int q = 0; q < 4; ++q) bb2[q] = b2l[w * 16 + kg * 4 + q];

    float ps[4] = {0.f, 0.f, 0.f, 0.f}, pq[4] = {0.f, 0.f, 0.f, 0.f};

    int bid = blockIdx.x;
    if (bid < T) stage_tile(zg, bid, zt[0], tid);
    __syncthreads();   // compiler drains vmcnt before barrier -> tile 0 ready

    int cur = 0;
    for (int t = bid; t < T; t += G) {
        int tn = t + G;
        if (tn < T) stage_tile(zg, tn, zt[cur ^ 1], tid);

        // ---- GEMM1: hid = relu(zg @ W1 + b1) ----
        const char* zc = zt[cur];
        f32x4 acc1[2][2];
#pragma unroll
        for (int nt = 0; nt < 2; ++nt)
#pragma unroll
            for (int s = 0; s < 2; ++s)
#pragma unroll
                for (int q = 0; q < 4; ++q) acc1[nt][s][q] = 0.f;

#pragma unroll
        for (int kk = 0; kk < 4; ++kk) {
            int ch = ((kk * 4 + kg) ^ (l15 & 7)) * 16;   // (s*16+l15)&7 == l15&7
            bf16x8 b0 = *(const bf16x8*)(zc + l15 * 256 + ch);
            bf16x8 b1v = *(const bf16x8*)(zc + (16 + l15) * 256 + ch);
            acc1[0][0] = MFMA(aW1[0][kk], b0, acc1[0][0]);
            acc1[0][1] = MFMA(aW1[0][kk], b1v, acc1[0][1]);
            acc1[1][0] = MFMA(aW1[1][kk], b0, acc1[1][0]);
            acc1[1][1] = MFMA(aW1[1][kk], b1v, acc1[1][1]);
        }
#pragma unroll
        for (int nt = 0; nt < 2; ++nt)
#pragma unroll
            for (int s = 0; s < 2; ++s) {
                bf16x4 hv;
#pragma unroll
                for (int q = 0; q < 4; ++q)
                    hv[q] = (__bf16)fmaxf(acc1[nt][s][q] + bb1[nt][q], 0.f);
                *(bf16x4*)&hid[s * 16 + l15][w * 32 + nt * 16 + kg * 4] = hv;
            }
        __syncthreads();   // hid complete (also completes prefetch)

        // ---- GEMM2: zp = hid @ W2 + b2 ----
        f32x4 acc2[2];
#pragma unroll
        for (int s = 0; s < 2; ++s)
#pragma unroll
            for (int q = 0; q < 4; ++q) acc2[s][q] = 0.f;
#pragma unroll
        for (int kk = 0; kk < 8; ++kk) {
            bf16x8 h0 = *(const bf16x8*)&hid[l15][kk * 32 + kg * 8];
            bf16x8 h1 = *(const bf16x8*)&hid[16 + l15][kk * 32 + kg * 8];
            acc2[0] = MFMA(aW2[kk], h0, acc2[0]);
            acc2[1] = MFMA(aW2[kk], h1, acc2[1]);
        }
        int rbase = t * 32;
#pragma unroll
        for (int s = 0; s < 2; ++s) {
            int r = rbase + s * 16 + l15;
            if (r < N) {
                bf16x4 ov;
#pragma unroll
                for (int q = 0; q < 4; ++q) {
                    float vv = acc2[s][q] + bb2[q];
                    ov[q] = (__bf16)vv;
                    ps[q] += vv;
                    pq[q] += vv * vv;
                }
                *(bf16x4*)(zpb + (size_t)r * H + w * 16 + kg * 4) = ov;
            }
        }
        __syncthreads();   // all waves done with hid & zt[cur]
        cur ^= 1;
    }

    // ---- BN partial stats: reduce over l15 lanes, one atomic per col ----
#pragma unroll
    for (int m = 1; m <= 8; m <<= 1) {
#pragma unroll
        for (int q = 0; q < 4; ++q) {
            ps[q] += __shfl_xor(ps[q], m);
            pq[q] += __shfl_xor(pq[q], m);
        }
    }
    if (l15 == 0) {
#pragma unroll
        for (int q = 0; q < 4; ++q) {
            atomicAdd(&stats[w * 16 + kg * 4 + q], ps[q]);
            atomicAdd(&stats[H + w * 16 + kg * 4 + q], pq[q]);
        }
    }
}

// ---------------------------------------------------------------------------
__global__ void bn_finalize_kernel(const float* __restrict__ stats,
                                   const float* __restrict__ gamma,
                                   const float* __restrict__ beta,
                                   float* __restrict__ ss, int N)
{
    int j = threadIdx.x;
    float invN = 1.0f / (float)N;
    float mean = stats[j] * invN;
    float var = stats[H + j] * invN - mean * mean;
    float sc = gamma[j] * rsqrtf(var + BN_EPS);
    ss[j] = sc;
    ss[H + j] = beta[j] - mean * sc;
}

// ---------------------------------------------------------------------------
// out = relu(zpb*scale + shift), bf16 -> fp32
__global__ __launch_bounds__(256) void bn_apply_kernel(
    const __bf16* __restrict__ zpb, const float* __restrict__ ss,
    float* __restrict__ out, int N)
{
    size_t i = (size_t)blockIdx.x * 256 + threadIdx.x;   // 8-elem units
    size_t total = (size_t)N * (H / 8);
    if (i >= total) return;
    int c8 = (int)(i & (H / 8 - 1));
    bf16x8 v = *(const bf16x8*)(zpb + i * 8);
    float4 o0, o1;
    const float* scp = &ss[c8 * 8];
    const float* shp = &ss[H + c8 * 8];
    o0.x = fmaxf((float)v[0] * scp[0] + shp[0], 0.f);
    o0.y = fmaxf((float)v[1] * scp[1] + shp[1], 0.f);
    o0.z = fmaxf((float)v[2] * scp[2] + shp[2], 0.f);
    o0.w = fmaxf((float)v[3] * scp[3] + shp[3], 0.f);
    o1.x = fmaxf((float)v[4] * scp[4] + shp[4], 0.f);
    o1.y = fmaxf((float)v[5] * scp[5] + shp[5], 0.f);
    o1.z = fmaxf((float)v[6] * scp[6] + shp[6], 0.f);
    o1.w = fmaxf((float)v[7] * scp[7] + shp[7], 0.f);
    ((float4*)out)[i * 2] = o0;
    ((float4*)out)[i * 2 + 1] = o1;
}

// ---------------------------------------------------------------------------
static inline char* align_up(char* p, size_t a) {
    return (char*)(((uintptr_t)p + a - 1) & ~(uintptr_t)(a - 1));
}

extern "C" void kernel_launch(void* const* d_in, const int* in_sizes, int n_in,
                              void* d_out, int out_size, void* d_ws, size_t ws_size,
                              hipStream_t stream)
{
    const float* x    = (const float*)d_in[0];
    const int*   ei   = (const int*)d_in[1];
    const float* embW = (const float*)d_in[2];
    const float* embb = (const float*)d_in[3];
    const float* W1   = (const float*)d_in[4];
    const float* b1   = (const float*)d_in[5];
    const float* W2   = (const float*)d_in[6];
    const float* b2   = (const float*)d_in[7];
    const float* gamma= (const float*)d_in[8];
    const float* beta = (const float*)d_in[9];

    int N = in_sizes[0] / NODE_IN;
    int E = in_sizes[1] / 2;
    int L = in_sizes[4] / (H * H2);
    const int* src = ei;
    const int* dst = ei + E;

    int numB = (N + 2047) / 2048;
    int T = (N + 31) / 32;           // 32-row tiles
    int G = T < 512 ? T : 512;       // mlp grid (persistent-ish blocks)

    char* w = (char*)d_ws;
    __bf16* zpb = (__bf16*)w;    w += (size_t)N * H * sizeof(__bf16);
    w = align_up(w, 256);
    char* zgb = w;               w += (size_t)T * 8192;
    w = align_up(w, 256);
    __bf16* h0 = (__bf16*)w;     w += (size_t)N * H * sizeof(__bf16);
    w = align_up(w, 256);
    float* statsAll = (float*)w; w += (size_t)L * 2 * H * sizeof(float);
    float* ss = (float*)w;       w += 2 * H * sizeof(float);
    int* deg = (int*)w;          w += (size_t)N * sizeof(int);
    int* offp = (int*)w;         w += (size_t)(N + 1) * sizeof(int);
    int* cursor = (int*)w;       w += (size_t)N * sizeof(int);
    int* bsum = (int*)w;         w += (size_t)numB * sizeof(int);
    int* srcl = (int*)w;         w += (size_t)E * sizeof(int);
    w = align_up(w, 256);
    __bf16* W1t = (__bf16*)w;    w += (size_t)L * H * H2 * sizeof(__bf16);
    w = align_up(w, 256);
    __bf16* W2t = (__bf16*)w;    w += (size_t)L * H * H2 * sizeof(__bf16);

    float* out = (float*)d_out;

    // ---- once-per-launch prep ----
    int wtotal2 = 2 * L * H * H2;
    convert_weights_kernel<<<(wtotal2 + 255) / 256, 256, 0, stream>>>(W1, W2, W1t, W2t, L);
    embed_kernel<<<(N + 15) / 16, 256, 0, stream>>>(x, embW, embb, h0, N);

    hipMemsetAsync(deg, 0, (size_t)N * sizeof(int), stream);
    hipMemsetAsync(statsAll, 0, (size_t)L * 2 * H * sizeof(float), stream);

    hist_kernel<<<(E + 255) / 256, 256, 0, stream>>>(dst, deg, E);
    scan_partial_kernel<<<numB, 256, 0, stream>>>(deg, bsum, N);
    scan_bsum_kernel<<<1, 256, 0, stream>>>(bsum, offp + N, numB);
    scan_apply_kernel<<<numB, 256, 0, stream>>>(deg, bsum, offp, cursor, N);
    fill_kernel<<<(E + 255) / 256, 256, 0, stream>>>(src, dst, cursor, srcl, E);

    int ggrid = (N * 16 + 255) / 256;
    int agrid = (int)(((size_t)N * (H / 8) + 255) / 256);

    for (int l = 0; l < L; ++l) {
        float* stats = statsAll + (size_t)l * 2 * H;
        const __bf16* hin = (l == 0) ? h0 : zpb;
        if (l == 0)
            gather_kernel<0><<<ggrid, 256, 0, stream>>>(hin, nullptr, offp, srcl, zgb, N);
        else
            gather_kernel<1><<<ggrid, 256, 0, stream>>>(hin, ss, offp, srcl, zgb, N);
        mlp_mfma_kernel<<<G, 512, 0, stream>>>(
            zgb, zpb, W1t + (size_t)l * H * H2, b1 + (size_t)l * H2,
            W2t + (size_t)l * H * H2, b2 + (size_t)l * H, stats, N, T, G);
        bn_finalize_kernel<<<1, H, 0, stream>>>(
            stats, gamma + (size_t)l * H, beta + (size_t)l * H, ss, N);
    }
    bn_apply_kernel<<<agrid, 256, 0, stream>>>(zpb, ss, out, N);
}